// Round 8
// baseline (2177.709 us; speedup 1.0000x reference)
//
#include <hip/hip_runtime.h>

typedef unsigned short ushort_t;
typedef unsigned int uint_t;

using f16x8 = __attribute__((ext_vector_type(8))) _Float16;
using f16x2 = __attribute__((ext_vector_type(2))) _Float16;
using f32x4 = __attribute__((ext_vector_type(4))) float;
using u32x4 = __attribute__((ext_vector_type(4))) unsigned int;

#define BATCH 64
#define SEQT 512
#define DIN 256
#define HID 256
#define G4 1024   // 4*HID

static __device__ __forceinline__ ushort_t f16b(float x) {
    return __builtin_bit_cast(ushort_t, (_Float16)x);
}
static __device__ __forceinline__ uint_t pk2(float a, float b) {
    return (uint_t)f16b(a) | ((uint_t)f16b(b) << 16);
}
static __device__ __forceinline__ float sig_(float x) {
    return 1.f / (1.f + __expf(-x));
}
static __device__ __forceinline__ float tanh_(float x) {
    float e = __expf(2.f * x);
    return (e - 1.f) / (e + 1.f);
}

// opaque pins: force residency in AGPR / VGPR (no remat, no spill rationale)
#define PINA(x) asm volatile("" : "+a"(x))
#define PINV(x) asm volatile("" : "+v"(x))

static __device__ __forceinline__ f16x8 asf16(u32x4 v) {
    return __builtin_bit_cast(f16x8, v);
}

// ---------------- prep kernels ----------------

__global__ void cvt_x_kernel(const float* __restrict__ in, ushort_t* __restrict__ out, int n4) {
    int i = blockIdx.x * blockDim.x + threadIdx.x;
    if (i < n4) {
        float4 v = ((const float4*)in)[i];
        ushort4 o;
        o.x = f16b(v.x); o.y = f16b(v.y); o.z = f16b(v.z); o.w = f16b(v.w);
        ((ushort4*)out)[i] = o;
    }
}

// W [256][1024] f32 -> Wt [1024][256] f16 bits (transpose)
__global__ void prep_wt_kernel(const float* __restrict__ W, ushort_t* __restrict__ Wt) {
    int tid = blockIdx.x * blockDim.x + threadIdx.x;
    int k = tid >> 10;
    int n = tid & 1023;
    Wt[n * DIN + k] = f16b(W[tid]);
}

// U [256][1024] f32 -> Upk [32][1024] uint4; Upk[j][g] = f16 pairs for k=8j..8j+7, col g
__global__ void prep_upk_kernel(const float* __restrict__ U, uint4* __restrict__ Upk) {
    int tid = blockIdx.x * blockDim.x + threadIdx.x;
    int j = tid >> 10;
    int g = tid & 1023;
    uint4 o;
    uint_t* op = &o.x;
#pragma unroll
    for (int q = 0; q < 4; ++q) {
        float a = U[(8 * j + 2 * q) * G4 + g];
        float b = U[(8 * j + 2 * q + 1) * G4 + g];
        op[q] = pk2(a, b);
    }
    Upk[tid] = o;
}

// ---------------- GEMM (unchanged, passing) ----------------

#define GSTRIDE 40

__global__ __launch_bounds__(256) void gemm_f16_kernel(
    const ushort_t* __restrict__ A,
    const ushort_t* __restrict__ Bt,
    const float* __restrict__ bias,
    float* __restrict__ C,
    int M)
{
    const int K = DIN, N = G4;
    __shared__ ushort_t As[128 * GSTRIDE];
    __shared__ ushort_t Bs[128 * GSTRIDE];
    int tid = threadIdx.x;
    int bx = blockIdx.x & 7;
    int by = blockIdx.x >> 3;
    int m0 = by * 128, n0 = bx * 128;
    int w = tid >> 6, lane = tid & 63;
    int wr = (w >> 1) * 64, wc = (w & 1) * 64;
    int r = lane & 15, kg = lane >> 4;

    f32x4 acc[4][4];
#pragma unroll
    for (int i = 0; i < 4; ++i)
#pragma unroll
        for (int j = 0; j < 4; ++j)
            acc[i][j] = f32x4{0.f, 0.f, 0.f, 0.f};

    for (int kt = 0; kt < K; kt += 32) {
        __syncthreads();
#pragma unroll
        for (int s = 0; s < 2; ++s) {
            int chunk = tid + s * 256;
            int row = chunk >> 2;
            int ko = (chunk & 3) * 8;
            uint4 va = *(const uint4*)(A + (size_t)(m0 + row) * K + kt + ko);
            *(uint4*)(&As[row * GSTRIDE + ko]) = va;
            uint4 vb = *(const uint4*)(Bt + (size_t)(n0 + row) * K + kt + ko);
            *(uint4*)(&Bs[row * GSTRIDE + ko]) = vb;
        }
        __syncthreads();
        f16x8 af[4], bf[4];
#pragma unroll
        for (int i = 0; i < 4; ++i) {
            af[i] = *(const f16x8*)(&As[(wr + i * 16 + r) * GSTRIDE + kg * 8]);
            bf[i] = *(const f16x8*)(&Bs[(wc + i * 16 + r) * GSTRIDE + kg * 8]);
        }
#pragma unroll
        for (int i = 0; i < 4; ++i)
#pragma unroll
            for (int j = 0; j < 4; ++j)
                acc[i][j] = __builtin_amdgcn_mfma_f32_16x16x32_f16(af[i], bf[j], acc[i][j], 0, 0, 0);
    }

#pragma unroll
    for (int i = 0; i < 4; ++i)
#pragma unroll
        for (int j = 0; j < 4; ++j) {
            int col = n0 + wc + j * 16 + r;
            float bv = bias[col];
#pragma unroll
            for (int v = 0; v < 4; ++v) {
                int rowg = m0 + wr + i * 16 + kg * 4 + v;
                C[(size_t)rowg * N + col] = acc[i][j][v] + bv;
            }
        }
}

// ---------------- LSTM recurrence via MFMA, 8 waves (2/SIMD) ----------------
// 1 WG (512 thr, 8 waves) per batch row. Wave w owns, per gate block gb,
// tiles nt = gb*16 + w*2 + ti (ti=0,1) -> cols gb*256 + w*32 + [0,32).
// Lane l: ti = (l>>4)&1, col-in-tile = l&15; lanes 32-63 duplicate 0-31.
// kt-outer MFMA loop keeps acc live-set at 32 regs, af at 4.
// U frags: kt0-3 pinned AGPR (128), kt4-5 pinned VGPR (64), kt6-7 LDS (128KB).

__global__ __launch_bounds__(512)
__attribute__((amdgpu_waves_per_eu(2, 2)))
void lstm_mfma4_kernel(
    const float* __restrict__ xz,     // [B*T][1024], bias included
    const uint4* __restrict__ Upk,    // [32][1024] uint4
    ushort_t* __restrict__ out_h16,
    float* __restrict__ out_f32,
    int T)
{
    __shared__ __align__(16) u32x4 Uld[8][2][8][64];    // 128 KB [wave][kt-6][gb*2+ti][lane]
    __shared__ __align__(16) ushort_t h16[2][HID];      // 1 KB double-buffered h

    const int tid = threadIdx.x;      // 0..511
    const int w = tid >> 6;           // wave 0..7
    const int l = tid & 63;           // lane
    const int lg = l >> 4;            // lane group 0..3 (A k-subchunk)
    const int lr = l & 15;            // col-in-tile
    const int b = blockIdx.x;
    const u32x4* Upk4 = (const u32x4*)Upk;

    const int ti_sel = lg & 1;                   // which of the wave's 2 tiles per gb
    const int hcol = w * 32 + ti_sel * 16 + lr;  // this lane's h column (dup for l>=32)
    const bool primary = (l < 32);

    // ---- preload U fragments ----
    u32x4 ua[32];   // [kt*8 + gb*2 + ti], kt 0..3 -> AGPR (128 regs)
    u32x4 uv[16];   // [k2*8 + gb*2 + ti], kt 4..5 -> VGPR (64 regs)
#pragma unroll
    for (int gb = 0; gb < 4; ++gb)
#pragma unroll
        for (int ti = 0; ti < 2; ++ti) {
            int col = (gb * 16 + w * 2 + ti) * 16 + lr;
            int fi = gb * 2 + ti;
#pragma unroll
            for (int kt = 0; kt < 4; ++kt)
                ua[kt * 8 + fi] = Upk4[(kt * 4 + lg) * 1024 + col];
#pragma unroll
            for (int k2 = 0; k2 < 2; ++k2)
                uv[k2 * 8 + fi] = Upk4[((4 + k2) * 4 + lg) * 1024 + col];
        }
#pragma unroll
    for (int i = 0; i < 32; ++i) PINA(ua[i]);
#pragma unroll
    for (int i = 0; i < 16; ++i) PINV(uv[i]);

    // ---- stage kt6-7 into LDS ----
#pragma unroll
    for (int gb = 0; gb < 4; ++gb)
#pragma unroll
        for (int ti = 0; ti < 2; ++ti) {
            int col = (gb * 16 + w * 2 + ti) * 16 + lr;
            int fi = gb * 2 + ti;
#pragma unroll
            for (int k2 = 0; k2 < 2; ++k2)
                Uld[w][k2][fi][l] = Upk4[((6 + k2) * 4 + lg) * 1024 + col];
        }

    if (tid < HID) h16[0][tid] = 0;

    // xz for t=0 (per-lane, 4 gate columns)
    const float* xz_b = xz + (size_t)b * T * G4;
    float xzc[4];
#pragma unroll
    for (int gb = 0; gb < 4; ++gb) xzc[gb] = xz_b[gb * 256 + hcol];

    float c = 0.f;
    size_t obase = (size_t)b * T * HID + hcol;
    __syncthreads();

    for (int t = 0; t < T; ++t) {
        const int cur = t & 1, nxt = cur ^ 1;

        // prefetch next xz into regs (hides under MFMAs)
        float xzn[4];
        {
            const float* xztn = xz_b + (size_t)((t + 1 < T) ? (t + 1) : t) * G4;
#pragma unroll
            for (int gb = 0; gb < 4; ++gb) xzn[gb] = xztn[gb * 256 + hcol];
        }

        f32x4 acc[4][2];
#pragma unroll
        for (int gb = 0; gb < 4; ++gb)
#pragma unroll
            for (int ti = 0; ti < 2; ++ti)
                acc[gb][ti] = f32x4{0.f, 0.f, 0.f, 0.f};

        __builtin_amdgcn_s_setprio(1);
        // kt-outer: af read (4 regs live), 8 independent acc chains
#pragma unroll
        for (int kt = 0; kt < 4; ++kt) {
            f16x8 af = *(const f16x8*)((const char*)h16[cur] + kt * 64 + lg * 16);
#pragma unroll
            for (int gb = 0; gb < 4; ++gb)
#pragma unroll
                for (int ti = 0; ti < 2; ++ti)
                    acc[gb][ti] = __builtin_amdgcn_mfma_f32_16x16x32_f16(
                        af, asf16(ua[kt * 8 + gb * 2 + ti]), acc[gb][ti], 0, 0, 0);
        }
#pragma unroll
        for (int k2 = 0; k2 < 2; ++k2) {
            f16x8 af = *(const f16x8*)((const char*)h16[cur] + (4 + k2) * 64 + lg * 16);
#pragma unroll
            for (int gb = 0; gb < 4; ++gb)
#pragma unroll
                for (int ti = 0; ti < 2; ++ti)
                    acc[gb][ti] = __builtin_amdgcn_mfma_f32_16x16x32_f16(
                        af, asf16(uv[k2 * 8 + gb * 2 + ti]), acc[gb][ti], 0, 0, 0);
        }
#pragma unroll
        for (int k2 = 0; k2 < 2; ++k2) {
            f16x8 af = *(const f16x8*)((const char*)h16[cur] + (6 + k2) * 64 + lg * 16);
#pragma unroll
            for (int gb = 0; gb < 4; ++gb)
#pragma unroll
                for (int ti = 0; ti < 2; ++ti) {
                    u32x4 ub = Uld[w][k2][gb * 2 + ti][l];
                    acc[gb][ti] = __builtin_amdgcn_mfma_f32_16x16x32_f16(
                        af, asf16(ub), acc[gb][ti], 0, 0, 0);
                }
        }
        __builtin_amdgcn_s_setprio(0);

        // extract z: lane's column is tile ti_sel, col lr (any C row — all equal)
        float zg[4];
#pragma unroll
        for (int gb = 0; gb < 4; ++gb)
            zg[gb] = (ti_sel ? acc[gb][1][0] : acc[gb][0][0]) + xzc[gb];

        // gates fully in-register
        c = sig_(zg[1]) * c + sig_(zg[0]) * tanh_(zg[2]);
        float h = sig_(zg[3]) * tanh_(c);

        if (primary) {
            h16[nxt][hcol] = f16b(h);
            if (out_f32) out_f32[obase] = h;
            else out_h16[obase] = f16b(h);
        }
        obase += HID;

#pragma unroll
        for (int gb = 0; gb < 4; ++gb) xzc[gb] = xzn[gb];

        __syncthreads();
    }
}

// ---------------- launch ----------------

extern "C" void kernel_launch(void* const* d_in, const int* in_sizes, int n_in,
                              void* d_out, int out_size, void* d_ws, size_t ws_size,
                              hipStream_t stream) {
    const float* x  = (const float*)d_in[0];
    const float* W0 = (const float*)d_in[1];
    const float* U0 = (const float*)d_in[2];
    const float* b0 = (const float*)d_in[3];
    const float* W1 = (const float*)d_in[4];
    const float* U1 = (const float*)d_in[5];
    const float* b1 = (const float*)d_in[6];
    float* out = (float*)d_out;

    const size_t M = (size_t)BATCH * SEQT;   // 32768

    char* ws = (char*)d_ws;
    ushort_t* xf16  = (ushort_t*)(ws);                        // 16 MB
    ushort_t* y1f16 = (ushort_t*)(ws + (16u << 20));          // 16 MB
    ushort_t* Wt0   = (ushort_t*)(ws + (32u << 20));          // 0.5 MB
    ushort_t* Wt1   = (ushort_t*)(ws + (32u << 20) + 524288); // 0.5 MB
    uint4*    Upk0  = (uint4*)   (ws + (33u << 20));          // 0.5 MB
    uint4*    Upk1  = (uint4*)   (ws + (33u << 20) + 524288); // 0.5 MB
    float*    xz    = (float*)   (ws + (34u << 20));          // 128 MB

    {
        int n4 = (int)(M * DIN / 4);
        cvt_x_kernel<<<dim3((n4 + 255) / 256), dim3(256), 0, stream>>>(x, xf16, n4);
        prep_wt_kernel<<<dim3(1024), dim3(256), 0, stream>>>(W0, Wt0);
        prep_wt_kernel<<<dim3(1024), dim3(256), 0, stream>>>(W1, Wt1);
        prep_upk_kernel<<<dim3(128), dim3(256), 0, stream>>>(U0, Upk0);
        prep_upk_kernel<<<dim3(128), dim3(256), 0, stream>>>(U1, Upk1);
    }

    // layer 1
    gemm_f16_kernel<<<dim3((int)(M / 128) * 8), dim3(256), 0, stream>>>(xf16, Wt0, b0, xz, (int)M);
    lstm_mfma4_kernel<<<dim3(BATCH), dim3(512), 0, stream>>>(xz, Upk0, y1f16, nullptr, SEQT);

    // layer 2
    gemm_f16_kernel<<<dim3((int)(M / 128) * 8), dim3(256), 0, stream>>>(y1f16, Wt1, b1, xz, (int)M);
    lstm_mfma4_kernel<<<dim3(BATCH), dim3(512), 0, stream>>>(xz, Upk1, nullptr, out, SEQT);
}